// Round 6
// baseline (1040.695 us; speedup 1.0000x reference)
//
#include <hip/hip_runtime.h>

// TransformerEncoder on MI355X (gfx950). fp32 I/O, bf16 MFMA compute.
// B=2, S=2048, E=1024, H=16, A=64, FF=4096. M = 4096 tokens.
//
// R6 structure: all matmul B-operands are pre-transposed ONCE into bf16 [n][k]
// row-major buffers -> every LDS staging op is an aligned vector row-copy
// (stride 72 u16 = 144B, 16B-aligned, 2-way bank aliasing = free). No
// transpose scatters (R5's 16..32-way conflict source, SQ_LDS_BANK_CONFLICT
// 2e7 on flash). GEMM: 128x128 tile, 4 waves, 4x4 16x16x32 frags. Flash:
// K-tile 64, all-bf16 staging, Q pre-scaled by 1/32 (exact), diagonal-only
// masking, reversed q0 order (longest first).
//
// FFN algebra: relu is AFTER the 2nd linear -> ff = relu(mha@W12 + b12),
// W12T = (W1@W2)^T = W2^T @ W1^T computed per-launch (A=W2T bf16, B=W1 rows).
//
// Memory plan (ws footprint 20.004 MB = R5's proven-safe size):
//   ws u16 [0,2MB)=WqT [2,4)=WkT [4,6)=WvT [6,14)=VbfT   (all dead by proj)
//   ws f32 [0,16MB) = res1 -> mha (from proj on)
//   ws u16 [16,18MB)=W12T [18,20)=WprojT ; ws f32 @20MB = b12 (4KB)
//   d_out enc slot: W2T [0,8) -> Kbf [0,8) ; Qbf->attnH [8,16) ; res2/ffout/
//                   encoded f32 (from FFN on).  K/V slots: final fp32 outputs.
//
// MFMA 16x16x32 bf16 layouts (guide-verified):
//   A[m][k]: m=lane&15, k=(lane>>4)*8+j ; B[k][n]=BT[n][k]: n=lane&15, same k
//   C/D: col=lane&15, row=(lane>>4)*4+reg

typedef unsigned short u16;
typedef unsigned int u32;
typedef __bf16 bf16x8 __attribute__((ext_vector_type(8)));
typedef float f32x4 __attribute__((ext_vector_type(4)));

__device__ __forceinline__ u16 f2bf(float f) {
    u32 x = __float_as_uint(f);
    x += 0x7fffu + ((x >> 16) & 1u);
    return (u16)(x >> 16);
}

// flags
#define F_RELU  1
#define F_AHEAD 2   // A is head-major [h][tok][64] (bf16)
#define F_ABF   8   // A is bf16
#define F_BHEAD 16  // BT head-major [h][64][1024]; C head-major [h][4096][64]
#define F_BF32  32  // BT is fp32 (convert at staging)
#define F_CBFT  64  // Cbf transposed-within-head [h][64][4096]

// ------------------------------------------------------- fp32 -> bf16 transpose
// out[z][c][r] = bf16(in[z][r][c]); tile 64x64.
__global__ void k_transpose(const float* __restrict__ in, u16* __restrict__ out,
                            int R, int C, long long zstride) {
    __shared__ __align__(16) u16 T[64 * 72];
    in  += (long long)blockIdx.z * zstride;
    out += (long long)blockIdx.z * zstride;
    const int tid = threadIdx.x;
    const int r0 = blockIdx.x * 64, c0 = blockIdx.y * 64;
#pragma unroll
    for (int it = 0; it < 4; ++it) {
        const int slot = tid + it * 256;
        const int r = slot >> 4, c4 = (slot & 15) * 4;
        float4 v = *(const float4*)(in + (long long)(r0 + r) * C + c0 + c4);
        T[(c4 + 0) * 72 + r] = f2bf(v.x);
        T[(c4 + 1) * 72 + r] = f2bf(v.y);
        T[(c4 + 2) * 72 + r] = f2bf(v.z);
        T[(c4 + 3) * 72 + r] = f2bf(v.w);
    }
    __syncthreads();
#pragma unroll
    for (int it = 0; it < 2; ++it) {
        const int slot = tid + it * 256;
        const int c = slot >> 3, r8 = (slot & 7) * 8;
        *(uint4*)(out + (long long)(c0 + c) * R + r0 + r8) = *(const uint4*)&T[c * 72 + r8];
    }
}

// ------------------------------------------------------- GEMM 128x128, BT input
// C[m,n] = sum_k Ain[m,k]*BT[n,k] (+bias)(relu?)(+resid)(+resid2).
// C (fp32) and/or Cbf (bf16, *cbscale) outputs. C/resid/resid2 may alias
// same-address read-before-write — no __restrict__ on them.
__launch_bounds__(256, 2)
__global__ void k_gemm(const void* Ain, const float* A2, const void* BTin,
                       float* C, u16* Cbf, float cbscale,
                       int K, int lda, int ldbt, int ldc,
                       const float* bias, const float* resid, const float* resid2,
                       int flags) {
    __shared__ __align__(16) u16 As[128 * 72];
    __shared__ __align__(16) u16 Bs[128 * 72];
    const int tid = threadIdx.x;
    const int wave = tid >> 6, lane = tid & 63, quad = lane >> 4, l16 = lane & 15;
    const int wr = wave >> 1, wc = wave & 1;
    const int m0 = blockIdx.x * 128, n0 = blockIdx.y * 128;

    f32x4 acc[4][4];
#pragma unroll
    for (int i = 0; i < 4; ++i)
#pragma unroll
        for (int g = 0; g < 4; ++g) acc[i][g] = (f32x4){0.f, 0.f, 0.f, 0.f};

    for (int kk = 0; kk < K; kk += 64) {
        __syncthreads();
        // ---- A staging [128 m][64 k]
        if (flags & F_ABF) {
            const u16* Ab = (const u16*)Ain;
#pragma unroll
            for (int it = 0; it < 4; ++it) {
                const int slot = tid + it * 256;
                const int row = slot >> 3, c8 = (slot & 7) * 8;
                long long off;
                if (flags & F_AHEAD)
                    off = (long long)(kk >> 6) * 262144LL + (long long)(m0 + row) * 64 + c8;
                else
                    off = (long long)(m0 + row) * lda + kk + c8;
                *(uint4*)&As[row * 72 + c8] = *(const uint4*)(Ab + off);
            }
        } else {
            const float* Af = (const float*)Ain;
#pragma unroll
            for (int it = 0; it < 8; ++it) {
                const int slot = tid + it * 256;
                const int row = slot >> 4, c4 = (slot & 15) * 4;
                const long long off = (long long)(m0 + row) * lda + kk + c4;
                float4 va = *(const float4*)(Af + off);
                if (A2) {
                    float4 vb = *(const float4*)(A2 + off);
                    va.x += vb.x; va.y += vb.y; va.z += vb.z; va.w += vb.w;
                }
                ushort4 s;
                s.x = f2bf(va.x); s.y = f2bf(va.y); s.z = f2bf(va.z); s.w = f2bf(va.w);
                *(ushort4*)&As[row * 72 + c4] = s;
            }
        }
        // ---- B staging: BT row-copy [128 n][64 k]
        if (flags & F_BF32) {
            const float* Bf = (const float*)BTin;
#pragma unroll
            for (int it = 0; it < 8; ++it) {
                const int slot = tid + it * 256;
                const int n = slot >> 4, c4 = (slot & 15) * 4;
                float4 v = *(const float4*)(Bf + (long long)(n0 + n) * ldbt + kk + c4);
                ushort4 s;
                s.x = f2bf(v.x); s.y = f2bf(v.y); s.z = f2bf(v.z); s.w = f2bf(v.w);
                *(ushort4*)&Bs[n * 72 + c4] = s;
            }
        } else {
            const u16* Bb = (const u16*)BTin;
#pragma unroll
            for (int it = 0; it < 4; ++it) {
                const int slot = tid + it * 256;
                const int n = slot >> 3, c8 = (slot & 7) * 8;
                const int nn = n0 + n;
                long long off;
                if (flags & F_BHEAD)
                    off = (long long)(nn >> 6) * 65536LL + (long long)(nn & 63) * 1024 + kk + c8;
                else
                    off = (long long)nn * ldbt + kk + c8;
                *(uint4*)&Bs[n * 72 + c8] = *(const uint4*)(Bb + off);
            }
        }
        __syncthreads();
#pragma unroll
        for (int ks = 0; ks < 2; ++ks) {
            bf16x8 af[4], bf[4];
#pragma unroll
            for (int i = 0; i < 4; ++i)
                af[i] = *(const bf16x8*)&As[(wr * 64 + i * 16 + l16) * 72 + ks * 32 + quad * 8];
#pragma unroll
            for (int g = 0; g < 4; ++g)
                bf[g] = *(const bf16x8*)&Bs[(wc * 64 + g * 16 + l16) * 72 + ks * 32 + quad * 8];
#pragma unroll
            for (int i = 0; i < 4; ++i)
#pragma unroll
                for (int g = 0; g < 4; ++g)
                    acc[i][g] = __builtin_amdgcn_mfma_f32_16x16x32_bf16(af[i], bf[g], acc[i][g], 0, 0, 0);
        }
    }

    // ---- epilogue
#pragma unroll
    for (int i = 0; i < 4; ++i)
#pragma unroll
        for (int g = 0; g < 4; ++g)
#pragma unroll
            for (int r = 0; r < 4; ++r) {
                const int row = m0 + wr * 64 + i * 16 + quad * 4 + r;
                const int col = n0 + wc * 64 + g * 16 + l16;
                float v = acc[i][g][r];
                if (bias) v += bias[col];
                if (flags & F_RELU) v = fmaxf(v, 0.f);
                if (resid)  v += resid [(long long)row * ldc + col];
                if (resid2) v += resid2[(long long)row * ldc + col];
                long long co;
                if (flags & F_BHEAD)
                    co = (long long)(col >> 6) * 262144LL + (long long)row * 64 + (col & 63);
                else
                    co = (long long)row * ldc + col;
                if (C) C[co] = v;
                if (Cbf) {
                    long long cbo = co;
                    if (flags & F_CBFT)
                        cbo = (long long)(col >> 6) * 262144LL + (long long)(col & 63) * 4096 + row;
                    Cbf[cbo] = f2bf(v * cbscale);
                }
            }
}

// ------------------------------------------------------- b12 = b1@W2 + b2
__global__ void k_b12(const float* __restrict__ b1, const float* __restrict__ W2,
                      const float* __restrict__ b2, float* __restrict__ b12) {
    const int o = blockIdx.x * 256 + threadIdx.x;
    float s = 0.f;
    for (int f = 0; f < 4096; ++f) s += b1[f] * W2[f * 1024 + o];
    b12[o] = s + b2[o];
}

// ------------------------------------------------------- flash attention
// All-bf16 staging: Qa [h][tok][64] (pre-scaled by 1/32), Kb [h][tok][64],
// VT [h][64][4096tok]. K-tile 64, causal, online softmax, in-place attnH
// over this block's own Q tile. q0 reversed (longest blocks dispatch first).
__launch_bounds__(256, 2)
__global__ void k_flash(u16* Qa, const u16* __restrict__ Kb, const u16* __restrict__ VT) {
    __shared__ __align__(16) u16 Qs[64 * 72];
    __shared__ __align__(16) u16 Ks[64 * 72];
    __shared__ __align__(16) u16 Vt[64 * 72];
    __shared__ __align__(16) u16 Pb[64 * 72];
    const int tid = threadIdx.x;
    const int wave = tid >> 6, lane = tid & 63, quad = lane >> 4, l16 = lane & 15;
    const int hb = blockIdx.y, h = hb >> 1, b = hb & 1;
    const int q0 = (int)(gridDim.x - 1 - blockIdx.x) * 64;
    u16* Qp = Qa + (long long)h * 262144 + (long long)b * 131072;
    const u16* Kp = Kb + (long long)h * 262144 + (long long)b * 131072;
    const u16* Vp = VT + (long long)h * 262144 + (long long)b * 2048;
    const float NEG = -1.0e30f;

    // stage Q [64][64] bf16
#pragma unroll
    for (int it = 0; it < 2; ++it) {
        const int slot = tid + it * 256;
        const int row = slot >> 3, c8 = (slot & 7) * 8;
        *(uint4*)&Qs[row * 72 + c8] = *(const uint4*)(Qp + (long long)(q0 + row) * 64 + c8);
    }
    __syncthreads();
    const bf16x8 aq0 = *(const bf16x8*)&Qs[(wave * 16 + l16) * 72 + quad * 8];
    const bf16x8 aq1 = *(const bf16x8*)&Qs[(wave * 16 + l16) * 72 + 32 + quad * 8];

    f32x4 o[4];
#pragma unroll
    for (int g = 0; g < 4; ++g) o[g] = (f32x4){0.f, 0.f, 0.f, 0.f};
    float mrow[4] = {NEG, NEG, NEG, NEG};
    float lrow[4] = {0.f, 0.f, 0.f, 0.f};

    u16* Pw = Pb + wave * 16 * 72;
    const int nit = q0 / 64 + 1;
    for (int it = 0; it < nit; ++it) {
        const int k0 = it * 64;
        __syncthreads();
        // stage K [64 key][64 e] and Vt [64 a][64 key] — pure bf16 row copies
#pragma unroll
        for (int st = 0; st < 2; ++st) {
            const int slot = tid + st * 256;
            const int row = slot >> 3, c8 = (slot & 7) * 8;
            *(uint4*)&Ks[row * 72 + c8] = *(const uint4*)(Kp + (long long)(k0 + row) * 64 + c8);
            *(uint4*)&Vt[row * 72 + c8] = *(const uint4*)(Vp + (long long)row * 4096 + k0 + c8);
        }
        __syncthreads();
        // scores: 4 groups of 16 keys
        f32x4 s[4];
#pragma unroll
        for (int g = 0; g < 4; ++g) {
            s[g] = (f32x4){0.f, 0.f, 0.f, 0.f};
            const bf16x8 bk0 = *(const bf16x8*)&Ks[(g * 16 + l16) * 72 + quad * 8];
            const bf16x8 bk1 = *(const bf16x8*)&Ks[(g * 16 + l16) * 72 + 32 + quad * 8];
            s[g] = __builtin_amdgcn_mfma_f32_16x16x32_bf16(aq0, bk0, s[g], 0, 0, 0);
            s[g] = __builtin_amdgcn_mfma_f32_16x16x32_bf16(aq1, bk1, s[g], 0, 0, 0);
        }
        const bool diag = (it == nit - 1);
        // online softmax per row
#pragma unroll
        for (int r = 0; r < 4; ++r) {
            const int qg = q0 + wave * 16 + quad * 4 + r;
            float v[4];
#pragma unroll
            for (int g = 0; g < 4; ++g) v[g] = s[g][r];
            if (diag) {
#pragma unroll
                for (int g = 0; g < 4; ++g)
                    if (k0 + g * 16 + l16 > qg) v[g] = NEG;
            }
            float tmax = fmaxf(fmaxf(v[0], v[1]), fmaxf(v[2], v[3]));
#pragma unroll
            for (int off = 1; off < 16; off <<= 1) tmax = fmaxf(tmax, __shfl_xor(tmax, off, 16));
            const float mo = mrow[r];
            const float mn = fmaxf(mo, tmax);
            const float alpha = __expf(mo - mn);
            float e[4], rs = 0.f;
#pragma unroll
            for (int g = 0; g < 4; ++g) { e[g] = __expf(v[g] - mn); rs += e[g]; }
#pragma unroll
            for (int off = 1; off < 16; off <<= 1) rs += __shfl_xor(rs, off, 16);
            lrow[r] = lrow[r] * alpha + rs;
            mrow[r] = mn;
#pragma unroll
            for (int g = 0; g < 4; ++g) {
                o[g][r] *= alpha;
                Pw[(quad * 4 + r) * 72 + g * 16 + l16] = f2bf(e[g]);
            }
        }
        __syncthreads();
        // PV: o += P @ V  (P A-layout via LDS round-trip; Vt rows = B frags)
        const bf16x8 ap0 = *(const bf16x8*)&Pw[l16 * 72 + quad * 8];
        const bf16x8 ap1 = *(const bf16x8*)&Pw[l16 * 72 + 32 + quad * 8];
#pragma unroll
        for (int g = 0; g < 4; ++g) {
            const bf16x8 bv0 = *(const bf16x8*)&Vt[(g * 16 + l16) * 72 + quad * 8];
            const bf16x8 bv1 = *(const bf16x8*)&Vt[(g * 16 + l16) * 72 + 32 + quad * 8];
            o[g] = __builtin_amdgcn_mfma_f32_16x16x32_bf16(ap0, bv0, o[g], 0, 0, 0);
            o[g] = __builtin_amdgcn_mfma_f32_16x16x32_bf16(ap1, bv1, o[g], 0, 0, 0);
        }
    }

    // epilogue: attnH bf16 in-place over this block's Q tile
#pragma unroll
    for (int r = 0; r < 4; ++r) {
        const float inv = 1.0f / lrow[r];
        const int srow = q0 + wave * 16 + quad * 4 + r;
#pragma unroll
        for (int g = 0; g < 4; ++g)
            Qp[(long long)srow * 64 + g * 16 + l16] = f2bf(o[g][r] * inv);
    }
}

// ------------------------------------------------------- layernorm (row 1024)
__global__ void k_ln(const float* in1, const float* in2,
                     const float* __restrict__ g, const float* __restrict__ be,
                     float* out) {
    __shared__ float red[8];
    const int m = blockIdx.x;
    const int tid = threadIdx.x;
    const int e0 = tid * 4;
    const long long bp = (long long)m * 1024;
    float4 v = *(const float4*)(in1 + bp + e0);
    if (in2) {
        float4 u = *(const float4*)(in2 + bp + e0);
        v.x += u.x; v.y += u.y; v.z += u.z; v.w += u.w;
    }
    float s1 = v.x + v.y + v.z + v.w;
    float s2 = v.x * v.x + v.y * v.y + v.z * v.z + v.w * v.w;
#pragma unroll
    for (int off = 1; off < 64; off <<= 1) {
        s1 += __shfl_xor(s1, off);
        s2 += __shfl_xor(s2, off);
    }
    if ((tid & 63) == 0) { red[tid >> 6] = s1; red[4 + (tid >> 6)] = s2; }
    __syncthreads();
    const float S1 = red[0] + red[1] + red[2] + red[3];
    const float S2 = red[4] + red[5] + red[6] + red[7];
    const float mean = S1 * (1.0f / 1024.0f);
    const float var = S2 * (1.0f / 1024.0f) - mean * mean;
    const float rstd = rsqrtf(var + 1e-5f);
    float4 ug = *(const float4*)(g + e0);
    float4 ub = *(const float4*)(be + e0);
    float4 o;
    o.x = (v.x - mean) * rstd * ug.x + ub.x;
    o.y = (v.y - mean) * rstd * ug.y + ub.y;
    o.z = (v.z - mean) * rstd * ug.z + ub.z;
    o.w = (v.w - mean) * rstd * ug.w + ub.w;
    *(float4*)(out + bp + e0) = o;
}

// ------------------------------------------------------- launch
extern "C" void kernel_launch(void* const* d_in, const int* in_sizes, int n_in,
                              void* d_out, int out_size, void* d_ws, size_t ws_size,
                              hipStream_t stream) {
    (void)in_sizes; (void)n_in; (void)out_size; (void)ws_size;
    const float* emb    = (const float*)d_in[0];
    const float* pos    = (const float*)d_in[1];
    const float* Wq     = (const float*)d_in[2];
    const float* Wk     = (const float*)d_in[3];
    const float* Wv     = (const float*)d_in[4];
    const float* Wproj  = (const float*)d_in[5];
    const float* W1     = (const float*)d_in[6];
    const float* b1     = (const float*)d_in[7];
    const float* W2     = (const float*)d_in[8];
    const float* b2     = (const float*)d_in[9];
    const float* g_attn = (const float*)d_in[10];
    const float* be_attn= (const float*)d_in[11];
    const float* g_ffn  = (const float*)d_in[12];
    const float* be_ffn = (const float*)d_in[13];
    const float* g_out  = (const float*)d_in[14];
    const float* be_out = (const float*)d_in[15];

    float* enc   = (float*)d_out;
    float* out_K = enc + 4194304;
    float* out_V = enc + 8388608;
    u16*   encu  = (u16*)d_out;

    float* ws  = (float*)d_ws;
    u16*   wsu = (u16*)d_ws;
    u16* WqT    = wsu;              // [0,2MB)
    u16* WkT    = wsu + 1048576;    // [2,4)
    u16* WvT    = wsu + 2097152;    // [4,6)
    u16* VbfT   = wsu + 3145728;    // [6,14)  [h][64][4096]
    u16* W12T   = wsu + 8388608;    // [16,18)
    u16* WprojT = wsu + 9437184;    // [18,20)
    float* b12  = ws + 5242880;     // [20MB,+4KB)
    float* res1 = ws;               // [0,16MB) fp32 (proj onward); = mha
    float* mha  = ws;
    u16* W2T = encu;                // enc[0,8MB) early
    u16* Kbf = encu;                // enc[0,8MB) after W12T-GEMM
    u16* Qbf = encu + 4194304;      // enc[8,16MB); becomes attnH

    // --- one-time transposes (fp32 -> bf16 [n][k])
    k_transpose<<<dim3(16, 1, 16), 256, 0, stream>>>(Wq, WqT, 1024, 64, 65536LL);
    k_transpose<<<dim3(16, 1, 16), 256, 0, stream>>>(Wk, WkT, 1024, 64, 65536LL);
    k_transpose<<<dim3(16, 1, 16), 256, 0, stream>>>(Wv, WvT, 1024, 64, 65536LL);
    k_transpose<<<dim3(16, 16, 1), 256, 0, stream>>>(Wproj, WprojT, 1024, 1024, 0LL);
    k_transpose<<<dim3(64, 16, 1), 256, 0, stream>>>(W2, W2T, 4096, 1024, 0LL);

    // --- W12T = W2^T @ W1^T  (A=W2T bf16 [1024][4096], BT=W1 rows fp32)
    k_gemm<<<dim3(8, 8), 256, 0, stream>>>(W2T, nullptr, W1, nullptr, W12T, 1.0f,
                                           4096, 4096, 4096, 1024,
                                           nullptr, nullptr, nullptr, F_ABF | F_BF32);
    k_b12<<<4, 256, 0, stream>>>(b1, W2, b2, b12);

    // --- QKV (x = emb+pos fused into A staging)
    k_gemm<<<dim3(32, 8), 256, 0, stream>>>(emb, pos, WqT, nullptr, Qbf, 0.03125f,
                                            1024, 1024, 1024, 64,
                                            nullptr, nullptr, nullptr, F_BHEAD);
    k_gemm<<<dim3(32, 8), 256, 0, stream>>>(emb, pos, WkT, out_K, Kbf, 1.0f,
                                            1024, 1024, 1024, 64,
                                            nullptr, nullptr, nullptr, F_BHEAD);
    k_gemm<<<dim3(32, 8), 256, 0, stream>>>(emb, pos, WvT, out_V, VbfT, 1.0f,
                                            1024, 1024, 1024, 64,
                                            nullptr, nullptr, nullptr, F_BHEAD | F_CBFT);
    // --- flash attention (attnH bf16 in-place over Qbf)
    k_flash<<<dim3(32, 32), 256, 0, stream>>>(Qbf, Kbf, VbfT);
    // --- res1 = attnH @ Wproj + emb + pos
    k_gemm<<<dim3(32, 8), 256, 0, stream>>>(Qbf, nullptr, WprojT, res1, nullptr, 1.0f,
                                            1024, 64, 1024, 1024,
                                            nullptr, emb, pos, F_AHEAD | F_ABF);
    k_ln<<<4096, 256, 0, stream>>>(res1, nullptr, g_attn, be_attn, mha);
    // --- res2 = relu(mha @ W12 + b12) + mha -> enc slot
    k_gemm<<<dim3(32, 8), 256, 0, stream>>>(mha, nullptr, W12T, enc, nullptr, 1.0f,
                                            1024, 1024, 1024, 1024,
                                            b12, mha, nullptr, F_RELU);
    k_ln<<<4096, 256, 0, stream>>>(enc, nullptr, g_ffn, be_ffn, enc);
    k_ln<<<4096, 256, 0, stream>>>(mha, enc, g_out, be_out, enc);
}